// Round 1
// baseline (23.836 us; speedup 1.0000x reference)
//
#include <hip/hip_runtime.h>

// SpodNet: per-batch sequential column sweep.
// Key simplification: output Theta never depends on W (the Sherman-Morrison
// half only updates W, which is dead for the output; theta_22 - schur + schur
// == theta_22 up to rounding). So per batch b, for c = 0..21:
//     v[j'] = Theta[minus[j'], c]   (== row c by symmetry, contiguous)
//     v'    = Wcol @ v
//     Theta[minus, c] = v'; Theta[c, minus] = v'   (diagonal untouched)
// 22x22 fp32, B=16384 -> memory-bound (~63 MB r+w).

#define PP 22
#define PM 21
#define BSTRIDE 520   // floats per batch in LDS (484 padded; 520%32=8 -> groups on distinct banks)

__global__ __launch_bounds__(64, 4)
void spodnet_sweep(const float* __restrict__ theta_in,
                   const float* __restrict__ wcol,
                   float* __restrict__ theta_out)
{
    __shared__ float lds[4 * BSTRIDE];   // 8320 B
    const int lane = threadIdx.x;        // 0..63
    const int sub  = lane >> 4;          // which of 4 batches
    const int l16  = lane & 15;

    const long b0 = (long)blockIdx.x * 4;
    const float* gin  = theta_in  + b0 * (PP * PP);
    float*       gout = theta_out + b0 * (PP * PP);

    // ---- stage 4 matrices to LDS, coalesced float4 ----
    {
        const float4* g4 = reinterpret_cast<const float4*>(gin);
        #pragma unroll
        for (int it = 0; it < 8; ++it) {
            int k = lane + it * 64;          // float4 chunk index, 0..483
            if (k < 484) {
                int batch = k / 121;         // 121 float4 per matrix
                int e4    = k - batch * 121;
                float4 v = g4[k];
                float4* l4 = reinterpret_cast<float4*>(&lds[batch * BSTRIDE]);
                l4[e4] = v;
            }
        }
    }

    // ---- preload Wcol rows into registers (lane l16 owns outputs l16 and l16+16) ----
    float wA[PM], wB[PM];
    {
        const int rA = l16;
        int rB = l16 + 16; if (rB > PM - 1) rB = PM - 1;   // clamp; results unused for l16>=5
        #pragma unroll
        for (int j = 0; j < PM; ++j) {
            wA[j] = wcol[rA * PM + j];
            wB[j] = wcol[rB * PM + j];
        }
    }

    __syncthreads();

    float* M = &lds[sub * BSTRIDE];

    // ---- sequential column sweep, fully unrolled ----
    #pragma unroll
    for (int c = 0; c < PP; ++c) {
        // read row c (== column c by symmetry): 22 floats, 11x ds_read_b64,
        // uniform address within each 16-lane group -> LDS broadcast
        float f[PP];
        {
            const float2* row = reinterpret_cast<const float2*>(&M[c * PP]);
            #pragma unroll
            for (int h = 0; h < 11; ++h) {
                float2 t = row[h];
                f[2 * h]     = t.x;
                f[2 * h + 1] = t.y;
            }
        }

        float acc1 = 0.f, acc2 = 0.f;
        #pragma unroll
        for (int j = 0; j < PM; ++j) {
            const int mj = j + (j >= c ? 1 : 0);   // compile-time (both loops unrolled)
            acc1 = fmaf(wA[j], f[mj], acc1);
            acc2 = fmaf(wB[j], f[mj], acc2);
        }

        // all lanes have read row c before anyone clobbers it
        __syncthreads();

        {
            const int mi1 = l16 + (l16 >= c ? 1 : 0);
            M[c * PP + mi1] = acc1;     // row write
            M[mi1 * PP + c] = acc1;     // symmetric column write
            if (l16 < 5) {
                const int i2  = l16 + 16;
                const int mi2 = i2 + (i2 >= c ? 1 : 0);
                M[c * PP + mi2] = acc2;
                M[mi2 * PP + c] = acc2;
            }
        }

        // writes visible before next column's reads
        __syncthreads();
    }

    // ---- store, coalesced float4 ----
    {
        float4* g4o = reinterpret_cast<float4*>(gout);
        #pragma unroll
        for (int it = 0; it < 8; ++it) {
            int k = lane + it * 64;
            if (k < 484) {
                int batch = k / 121;
                int e4    = k - batch * 121;
                const float4* l4 = reinterpret_cast<const float4*>(&lds[batch * BSTRIDE]);
                g4o[k] = l4[e4];
            }
        }
    }
}

extern "C" void kernel_launch(void* const* d_in, const int* in_sizes, int n_in,
                              void* d_out, int out_size, void* d_ws, size_t ws_size,
                              hipStream_t stream) {
    const float* theta = (const float*)d_in[0];
    const float* wcol  = (const float*)d_in[1];
    float* out = (float*)d_out;

    const int Btot = in_sizes[0] / (PP * PP);   // 16384
    const int grid = Btot / 4;                  // 4 batches per 64-thread block
    hipLaunchKernelGGL(spodnet_sweep, dim3(grid), dim3(64), 0, stream,
                       theta, wcol, out);
}

// Round 2
// 21.928 us; speedup vs baseline: 1.0870x; 1.0870x over previous
//
#include <hip/hip_runtime.h>

// SpodNet: per-batch sequential column sweep (B=16384 independent 22x22 fp32).
// Output Theta never depends on W; per batch, for c = 0..21:
//   u = row c (updated prefix from earlier columns' writes, original suffix)
//   v' = Wcol @ u(minus c) ; written symmetrically into row/column c.
// Round 2: 8-lane groups (8 batches/wave), global_load_lds staging, no
// barriers (single-wave blocks, in-order LDS), dead row-writes skipped.

#define PP 22
#define PM 21
#define MAT 484                  // floats per matrix
#define TB 8                     // batches per block (one wave, 8 lanes each)
#define TILE_FLOATS (TB * MAT)   // 3872 floats
#define TILE_BYTES  (TILE_FLOATS * 4)  // 15488 B

typedef const __attribute__((address_space(1))) void* gas_ptr;
typedef __attribute__((address_space(3))) void* las_ptr;

__global__ __launch_bounds__(64, 4)
void spodnet_sweep(const float* __restrict__ theta_in,
                   const float* __restrict__ wcol,
                   float* __restrict__ theta_out)
{
    __shared__ float lds[TILE_FLOATS];   // 15488 B, linear (no padding: glds dest)
    const int lane = threadIdx.x;        // 0..63
    const int g = lane >> 3;             // batch within tile
    const int k = lane & 7;              // lane within 8-lane group

    const long b0 = (long)blockIdx.x * TB;
    const float* gin  = theta_in  + b0 * MAT;
    float*       gout = theta_out + b0 * MAT;

    // ---- async stage: global -> LDS, linear, 16 B/lane ----
    {
        const char* src = (const char*)gin;
        #pragma unroll
        for (int it = 0; it < 15; ++it) {
            __builtin_amdgcn_global_load_lds(
                (gas_ptr)(src + it * 1024 + lane * 16),
                (las_ptr)((char*)lds + it * 1024),
                16, 0, 0);
        }
        if (lane < 8) {   // tail: 15488 - 15*1024 = 128 B
            __builtin_amdgcn_global_load_lds(
                (gas_ptr)(src + 15360 + lane * 16),
                (las_ptr)((char*)lds + 15360),
                16, 0, 0);
        }
    }

    // ---- Wcol rows k, k+8, k+16 (clamped; lanes k>=5 never write acc2) ----
    float w0[PM], w1[PM], w2[PM];
    {
        const int r0 = k, r1 = k + 8, r2 = (k < 5) ? (k + 16) : 20;
        #pragma unroll
        for (int j = 0; j < PM; ++j) {
            w0[j] = wcol[r0 * PM + j];
            w1[j] = wcol[r1 * PM + j];
            w2[j] = wcol[r2 * PM + j];
        }
    }

    // fence: LDS reads below must not start before the DMA completes
    asm volatile("s_waitcnt vmcnt(0)" ::: "memory");
    __builtin_amdgcn_sched_barrier(0);

    float* M = &lds[g * MAT];

    // ---- sequential column sweep, fully unrolled (static reg indexing) ----
    #pragma unroll
    for (int c = 0; c < PP; ++c) {
        float f[PP];
        {
            const float2* row = reinterpret_cast<const float2*>(&M[c * PP]);
            #pragma unroll
            for (int h = 0; h < 11; ++h) {
                float2 t = row[h];
                f[2 * h]     = t.x;
                f[2 * h + 1] = t.y;
            }
        }

        // 3 outputs/lane, each as 2 partial chains (shorter dep chain)
        float a0 = 0.f, a1 = 0.f, a2 = 0.f;
        float b0a = 0.f, b1a = 0.f, b2a = 0.f;
        #pragma unroll
        for (int j = 0; j < PM; ++j) {
            const int mj = j + (j >= c ? 1 : 0);   // compile-time
            if (j < 11) {
                a0 = fmaf(w0[j], f[mj], a0);
                a1 = fmaf(w1[j], f[mj], a1);
                a2 = fmaf(w2[j], f[mj], a2);
            } else {
                b0a = fmaf(w0[j], f[mj], b0a);
                b1a = fmaf(w1[j], f[mj], b1a);
                b2a = fmaf(w2[j], f[mj], b2a);
            }
        }
        a0 += b0a; a1 += b1a; a2 += b2a;

        // column writes [mi, c]: always needed (read at step mi, or final)
        const int mi0 = k      + (k      >= c ? 1 : 0);
        const int mi1 = k + 8  + (k + 8  >= c ? 1 : 0);
        const int mi2 = k + 16 + (k + 16 >= c ? 1 : 0);
        M[mi0 * PP + c] = a0;
        M[mi1 * PP + c] = a1;
        if (k < 5) M[mi2 * PP + c] = a2;
        // row writes [c, mi]: only mi < c are final; mi > c would be
        // overwritten at step mi before any read -> skip (dead)
        if (mi0 < c) M[c * PP + mi0] = a0;
        if (mi1 < c) M[c * PP + mi1] = a1;
        if (k < 5 && mi2 < c) M[c * PP + mi2] = a2;
    }

    // ---- store: LDS -> global, coalesced float4 ----
    {
        const float4* l4 = reinterpret_cast<const float4*>(lds);
        float4* g4 = reinterpret_cast<float4*>(gout);
        #pragma unroll
        for (int it = 0; it < 15; ++it)
            g4[it * 64 + lane] = l4[it * 64 + lane];
        if (lane < 8)
            g4[960 + lane] = l4[960 + lane];   // tail: 968 float4 total
    }
}

extern "C" void kernel_launch(void* const* d_in, const int* in_sizes, int n_in,
                              void* d_out, int out_size, void* d_ws, size_t ws_size,
                              hipStream_t stream) {
    const float* theta = (const float*)d_in[0];
    const float* wcol  = (const float*)d_in[1];
    float* out = (float*)d_out;

    const int Btot = in_sizes[0] / (PP * PP);   // 16384
    const int grid = Btot / TB;                 // 2048 blocks, 8 per CU
    hipLaunchKernelGGL(spodnet_sweep, dim3(grid), dim3(64), 0, stream,
                       theta, wcol, out);
}